// Round 3
// baseline (485.661 us; speedup 1.0000x reference)
//
#include <hip/hip_runtime.h>
#include <hip/hip_bf16.h>

#define IN_SIZE 4096
#define OUT_SIZE 4096
#define BATCH 4096

typedef __bf16 bf16x8 __attribute__((ext_vector_type(8)));
typedef float f32x4 __attribute__((ext_vector_type(4)));

// ---------------------------------------------------------------- W build
// Strategy: duplicate-summing COO scatter == device-scope fp32 atomicAdd into
// a dense W. Done in two row-halves (32 MB each) so the atomic working set is
// L2/L3-resident and total workspace stays at 96 MB. No binning, no sort, no
// per-entry search — 4.19M independent atomics, latency hidden by TLP.

// prep: zero the 32MB fp32 half-W; on the first pass also convert x -> bf16.
__global__ __launch_bounds__(256) void prep_kernel(f32x4* __restrict__ w4,
                                                   const f32x4* __restrict__ xin,
                                                   bf16x8* __restrict__ xout,
                                                   int do_x) {
    const int gtid = blockIdx.x * 256 + threadIdx.x;
    const int stride = gridDim.x * 256;
    const f32x4 z = {0.f, 0.f, 0.f, 0.f};
    for (int i = gtid; i < (OUT_SIZE / 2) * IN_SIZE / 4; i += stride) w4[i] = z;
    if (do_x) {
        for (int t = gtid; t < BATCH * IN_SIZE / 8; t += stride) {
            const f32x4 a = xin[2 * t];
            const f32x4 b = xin[2 * t + 1];
            bf16x8 o;
            o[0] = (__bf16)a[0]; o[1] = (__bf16)a[1]; o[2] = (__bf16)a[2]; o[3] = (__bf16)a[3];
            o[4] = (__bf16)b[0]; o[5] = (__bf16)b[1]; o[6] = (__bf16)b[2]; o[7] = (__bf16)b[3];
            xout[t] = o;
        }
    }
}

// scatter: vectorized read of (vals, iin, iout), one global fp32 atomicAdd per
// entry whose iout falls in [rowbase, rowbase+2048).
__global__ __launch_bounds__(256) void scatter_kernel(const float* __restrict__ vals,
                                                      const int* __restrict__ iin,
                                                      const int* __restrict__ iout,
                                                      float* __restrict__ W32h,
                                                      int nnz, int rowbase) {
    const int gtid = blockIdx.x * 256 + threadIdx.x;
    const int stride = gridDim.x * 256;
    const int nv = nnz >> 2;
    const float4* v4 = (const float4*)vals;
    const int4*   a4 = (const int4*)iin;
    const int4*   b4 = (const int4*)iout;
    for (int i = gtid; i < nv; i += stride) {
        const float4 v = v4[i];
        const int4   a = a4[i];
        const int4   b = b4[i];
        int r;
        r = b.x - rowbase; if ((unsigned)r < 2048u) atomicAdd(&W32h[(size_t)r * IN_SIZE + a.x], v.x);
        r = b.y - rowbase; if ((unsigned)r < 2048u) atomicAdd(&W32h[(size_t)r * IN_SIZE + a.y], v.y);
        r = b.z - rowbase; if ((unsigned)r < 2048u) atomicAdd(&W32h[(size_t)r * IN_SIZE + a.z], v.z);
        r = b.w - rowbase; if ((unsigned)r < 2048u) atomicAdd(&W32h[(size_t)r * IN_SIZE + a.w], v.w);
    }
    for (int k = (nv << 2) + gtid; k < nnz; k += stride) {
        const int r = iout[k] - rowbase;
        if ((unsigned)r < 2048u) atomicAdd(&W32h[(size_t)r * IN_SIZE + iin[k]], vals[k]);
    }
}

// convert the accumulated fp32 half-W to bf16 (vec8 stores).
__global__ __launch_bounds__(256) void wcvt_kernel(const f32x4* __restrict__ w4,
                                                   bf16x8* __restrict__ out) {
    const int gtid = blockIdx.x * 256 + threadIdx.x;
    const int stride = gridDim.x * 256;
    for (int t = gtid; t < (OUT_SIZE / 2) * IN_SIZE / 8; t += stride) {
        const f32x4 a = w4[2 * t];
        const f32x4 b = w4[2 * t + 1];
        bf16x8 o;
        o[0] = (__bf16)a[0]; o[1] = (__bf16)a[1]; o[2] = (__bf16)a[2]; o[3] = (__bf16)a[3];
        o[4] = (__bf16)b[0]; o[5] = (__bf16)b[1]; o[6] = (__bf16)b[2]; o[7] = (__bf16)b[3];
        out[t] = o;
    }
}

// ----------------------------------------------------------------- GEMM
// C[M][N] = A[M][K] * B[N][K]^T, all 4096, A/B bf16 row-major, C fp32.
// 256x256 tile, BK=32, 8 waves (2M x 4N), 8x4 16x16x32-bf16 frags/wave.
// 4-deep LDS pipeline (4 x 32 KB = 128 KB), counted vmcnt(8) per K-tile
// (loads for tiles t+2,t+3 stay in flight across barriers), raw s_barrier,
// setprio(1) around MFMA clusters, bijective XCD blockIdx swizzle.
// XOR swizzle at 16B-chunk granularity (slot = q ^ ((row>>1)&3)), applied
// on the pre-swizzled GLOBAL source (global_load_lds dest must be linear).
// [verified round 2: 127 us, MfmaUtil 46.5%, bank conflicts 0 — unchanged]
#define GNT 128   // 4096 / BK(=32)

#define STAGE_A(T)                                                            \
  do {                                                                        \
    const __bf16* s_ = gA0 + (size_t)(T) * 32;                                \
    __bf16* d_ = &smem[((T) & 3) * 16384 + tid * 8];                          \
    __builtin_amdgcn_global_load_lds(                                         \
        (const __attribute__((address_space(1))) void*)s_,                    \
        (__attribute__((address_space(3))) void*)d_, 16, 0, 0);               \
    __builtin_amdgcn_global_load_lds(                                         \
        (const __attribute__((address_space(1))) void*)(s_ + (size_t)524288), \
        (__attribute__((address_space(3))) void*)(d_ + 4096), 16, 0, 0);      \
  } while (0)

#define STAGE_B(T)                                                            \
  do {                                                                        \
    const __bf16* s_ = gB0 + (size_t)(T) * 32;                                \
    __bf16* d_ = &smem[((T) & 3) * 16384 + 8192 + tid * 8];                   \
    __builtin_amdgcn_global_load_lds(                                         \
        (const __attribute__((address_space(1))) void*)s_,                    \
        (__attribute__((address_space(3))) void*)d_, 16, 0, 0);               \
    __builtin_amdgcn_global_load_lds(                                         \
        (const __attribute__((address_space(1))) void*)(s_ + (size_t)524288), \
        (__attribute__((address_space(3))) void*)(d_ + 4096), 16, 0, 0);      \
  } while (0)

#define VMW8 asm volatile("s_waitcnt vmcnt(8)" ::: "memory")
#define VMW4 asm volatile("s_waitcnt vmcnt(4)" ::: "memory")
#define VMW0 asm volatile("s_waitcnt vmcnt(0)" ::: "memory")
#define VMWN ((void)0)

#define GTILE(T, DOSTAGE, VMWAIT, ENDBAR)                                     \
  do {                                                                        \
    const __bf16* bp_ = &smem[((T) & 3) * 16384];                             \
    bf16x8 bfr_[4], af_[4];                                                   \
    _Pragma("unroll") for (int j_ = 0; j_ < 4; ++j_)                          \
        bfr_[j_] = *(const bf16x8*)(bp_ + offB[j_]);                          \
    _Pragma("unroll") for (int i_ = 0; i_ < 4; ++i_)                          \
        af_[i_] = *(const bf16x8*)(bp_ + offA[i_]);                           \
    if (DOSTAGE) STAGE_A((T) + 3);                                            \
    __builtin_amdgcn_s_barrier();                                             \
    __builtin_amdgcn_s_setprio(1);                                            \
    _Pragma("unroll") for (int i_ = 0; i_ < 4; ++i_)                          \
        _Pragma("unroll") for (int j_ = 0; j_ < 4; ++j_)                      \
            acc[i_][j_] = __builtin_amdgcn_mfma_f32_16x16x32_bf16(            \
                af_[i_], bfr_[j_], acc[i_][j_], 0, 0, 0);                     \
    __builtin_amdgcn_s_setprio(0);                                            \
    __builtin_amdgcn_s_barrier();                                             \
    _Pragma("unroll") for (int i_ = 0; i_ < 4; ++i_)                          \
        af_[i_] = *(const bf16x8*)(bp_ + offA[4 + i_]);                       \
    if (DOSTAGE) STAGE_B((T) + 3);                                            \
    __builtin_amdgcn_s_barrier();                                             \
    __builtin_amdgcn_s_setprio(1);                                            \
    _Pragma("unroll") for (int i_ = 0; i_ < 4; ++i_)                          \
        _Pragma("unroll") for (int j_ = 0; j_ < 4; ++j_)                      \
            acc[4 + i_][j_] = __builtin_amdgcn_mfma_f32_16x16x32_bf16(        \
                af_[i_], bfr_[j_], acc[4 + i_][j_], 0, 0, 0);                 \
    __builtin_amdgcn_s_setprio(0);                                            \
    asm volatile("s_waitcnt lgkmcnt(0)" ::: "memory");                        \
    VMWAIT;                                                                   \
    if (ENDBAR) __builtin_amdgcn_s_barrier();                                 \
  } while (0)

__global__ __launch_bounds__(512, 2) void gemm_bt_kernel(
    const __bf16* __restrict__ A,
    const __bf16* __restrict__ B,
    float* __restrict__ C) {
    __shared__ __bf16 smem[4 * 16384];   // 128 KB: 4 bufs x (A 8192 | B 8192)

    const int tid   = threadIdx.x;
    const int lane  = tid & 63;
    const int wv    = tid >> 6;
    const int wm    = wv >> 2;           // 0..1  -> 128 M-rows each
    const int wn    = wv & 3;            // 0..3  -> 64 N-cols each
    const int row16 = lane & 15;
    const int quad  = lane >> 4;

    // bijective XCD swizzle: 256 blocks, 8 XCDs, 32 contiguous tiles/XCD
    const int swz = (blockIdx.x & 7) * 32 + (blockIdx.x >> 3);
    const int bm  = (swz >> 4) * 256;
    const int bn  = (swz & 15) * 256;

    // staging: 512 thr x 16B = 8 KB = 128 rows of 64 B; 2 issues per matrix.
    // slot p holds pre-swizzle chunk q = p ^ ((row>>1)&3)  (inverse == itself)
    const int sr = tid >> 2;                       // local row 0..127
    const int sq = (tid & 3) ^ ((sr >> 1) & 3);    // source 16B-chunk
    const __bf16* gA0 = A + (size_t)(bm + sr) * 4096 + sq * 8;
    const __bf16* gB0 = B + (size_t)(bn + sr) * 4096 + sq * 8;

    // ds_read element offsets (per-lane, constant across tiles)
    int offA[8], offB[4];
#pragma unroll
    for (int i = 0; i < 8; ++i) {
        const int ra = wm * 128 + i * 16 + row16;
        offA[i] = ra * 32 + ((quad ^ ((ra >> 1) & 3)) * 8);
    }
#pragma unroll
    for (int j = 0; j < 4; ++j) {
        const int rb = wn * 64 + j * 16 + row16;
        offB[j] = 8192 + rb * 32 + ((quad ^ ((rb >> 1) & 3)) * 8);
    }

    f32x4 acc[8][4] = {};

    // prologue: tiles 0..2 in flight (12 loads), land tile 0
    STAGE_A(0); STAGE_B(0);
    STAGE_A(1); STAGE_B(1);
    STAGE_A(2); STAGE_B(2);
    VMW8;
    __builtin_amdgcn_s_barrier();

    int t = 0;
    for (; t < GNT - 3; ++t) GTILE(t, true, VMW8, true);
    GTILE(t, false, VMW4, true); ++t;
    GTILE(t, false, VMW0, true); ++t;
    GTILE(t, false, VMWN, false);

#pragma unroll
    for (int i = 0; i < 8; ++i) {
        const int rbase = bm + wm * 128 + i * 16 + quad * 4;
#pragma unroll
        for (int j = 0; j < 4; ++j) {
            const int col = bn + wn * 64 + j * 16 + row16;
#pragma unroll
            for (int r = 0; r < 4; ++r)
                C[(size_t)(rbase + r) * 4096 + col] = acc[i][j][r];
        }
    }
}

extern "C" void kernel_launch(void* const* d_in, const int* in_sizes, int n_in,
                              void* d_out, int out_size, void* d_ws, size_t ws_size,
                              hipStream_t stream) {
    const float* x    = (const float*)d_in[0];
    const float* vals = (const float*)d_in[1];
    const int*   iin  = (const int*)d_in[2];
    const int*   iout = (const int*)d_in[3];
    float*       C    = (float*)d_out;
    const int    nnz  = in_sizes[1];

    // workspace: Wb 32MB | Xb 32MB | W32half 32MB  = 96 MB
    char*   ws   = (char*)d_ws;
    __bf16* Wb   = (__bf16*)ws;
    __bf16* Xb   = (__bf16*)(ws + ((size_t)32 << 20));
    float*  W32h = (float*)(ws + ((size_t)64 << 20));

    // pass 0: rows [0, 2048)
    prep_kernel<<<2048, 256, 0, stream>>>((f32x4*)W32h, (const f32x4*)x, (bf16x8*)Xb, 1);
    scatter_kernel<<<2048, 256, 0, stream>>>(vals, iin, iout, W32h, nnz, 0);
    wcvt_kernel<<<2048, 256, 0, stream>>>((const f32x4*)W32h, (bf16x8*)Wb);
    // pass 1: rows [2048, 4096)
    prep_kernel<<<2048, 256, 0, stream>>>((f32x4*)W32h, (const f32x4*)x, (bf16x8*)Xb, 0);
    scatter_kernel<<<2048, 256, 0, stream>>>(vals, iin, iout, W32h, nnz, 2048);
    wcvt_kernel<<<2048, 256, 0, stream>>>((const f32x4*)W32h,
                                          (bf16x8*)(Wb + (size_t)2048 * IN_SIZE));

    gemm_bt_kernel<<<256, 512, 0, stream>>>(Xb, Wb, C);
}

// Round 4
// 378.577 us; speedup vs baseline: 1.2829x; 1.2829x over previous
//
#include <hip/hip_runtime.h>
#include <hip/hip_bf16.h>

#define IN_SIZE 4096
#define OUT_SIZE 4096
#define BATCH 4096

// counting-sort parameters: 512 source blocks x 8192 entries; 1024 cells of
// 4 W-rows. Exact global segment offsets via (cell,block) count matrix + scan.
#define NBLK 512
#define CHUNK 8192
#define NCELL 1024

typedef __bf16 bf16x8 __attribute__((ext_vector_type(8)));
typedef float f32x4 __attribute__((ext_vector_type(4)));

// ---------------------------------------------------- K1: per-block histogram
__global__ __launch_bounds__(256) void hist_kernel(const int* __restrict__ iout,
                                                   int* __restrict__ cnt, int nnz) {
    __shared__ int hist[NCELL];
    const int b = blockIdx.x, tid = threadIdx.x;
    for (int c = tid; c < NCELL; c += 256) hist[c] = 0;
    __syncthreads();
    const int gbase = b * (CHUNK / 4);
    const int4* io4 = (const int4*)iout;
    for (int i = tid; i < CHUNK / 4; i += 256) {
        const int g = gbase + i;
        if (g * 4 + 3 < nnz) {
            const int4 o = io4[g];
            atomicAdd(&hist[o.x >> 2], 1);
            atomicAdd(&hist[o.y >> 2], 1);
            atomicAdd(&hist[o.z >> 2], 1);
            atomicAdd(&hist[o.w >> 2], 1);
        } else {
            const int ke = (nnz < g * 4 + 4) ? nnz : g * 4 + 4;
            for (int k = g * 4; k < ke; ++k) atomicAdd(&hist[iout[k] >> 2], 1);
        }
    }
    __syncthreads();
    for (int c = tid; c < NCELL; c += 256) cnt[c * NBLK + b] = hist[c];
}

// ---------------- K2a: per-cell exclusive scan across 512 blocks (in place)
__global__ __launch_bounds__(256) void scanb_kernel(int* __restrict__ cnt,
                                                    int* __restrict__ celltot) {
    __shared__ int partial[256];
    const int c = blockIdx.x, tid = threadIdx.x;
    int* row = cnt + c * NBLK;
    const int v0 = row[2 * tid], v1 = row[2 * tid + 1];
    const int mysum = v0 + v1;
    partial[tid] = mysum;
    __syncthreads();
    for (int d = 1; d < 256; d <<= 1) {
        const int v = (tid >= d) ? partial[tid - d] : 0;
        __syncthreads();
        partial[tid] += v;
        __syncthreads();
    }
    const int excl = partial[tid] - mysum;
    row[2 * tid]     = excl;
    row[2 * tid + 1] = excl + v0;
    if (tid == 255) celltot[c] = partial[255];
}

// ---------------- K2b: exclusive scan of the 1024 cell totals -> cellbase
__global__ __launch_bounds__(256) void scanc_kernel(const int* __restrict__ celltot,
                                                    int* __restrict__ cellbase) {
    __shared__ int partial[256];
    const int tid = threadIdx.x;
    const int h0 = celltot[4 * tid],     h1 = celltot[4 * tid + 1];
    const int h2 = celltot[4 * tid + 2], h3 = celltot[4 * tid + 3];
    const int mysum = h0 + h1 + h2 + h3;
    partial[tid] = mysum;
    __syncthreads();
    for (int d = 1; d < 256; d <<= 1) {
        const int v = (tid >= d) ? partial[tid - d] : 0;
        __syncthreads();
        partial[tid] += v;
        __syncthreads();
    }
    const int excl = partial[tid] - mysum;
    cellbase[4 * tid]     = excl;
    cellbase[4 * tid + 1] = excl + h0;
    cellbase[4 * tid + 2] = excl + h0 + h1;
    cellbase[4 * tid + 3] = excl + h0 + h1 + h2;
    if (tid == 255) cellbase[NCELL] = partial[255];
}

// -------- K3: scatter entries directly to final cell-sorted global position
__global__ __launch_bounds__(256) void scatter_kernel(const float* __restrict__ vals,
                                                      const int* __restrict__ iin,
                                                      const int* __restrict__ iout,
                                                      const int* __restrict__ cnt,
                                                      const int* __restrict__ cellbase,
                                                      uint2* __restrict__ bkt, int nnz) {
    __shared__ int goff[NCELL];
    const int b = blockIdx.x, tid = threadIdx.x;
    for (int c = tid; c < NCELL; c += 256)
        goff[c] = cellbase[c] + cnt[c * NBLK + b];
    __syncthreads();
    const int gbase = b * (CHUNK / 4);
    const float4* v4 = (const float4*)vals;
    const int4*   a4 = (const int4*)iin;
    const int4*   o4 = (const int4*)iout;
    for (int i = tid; i < CHUNK / 4; i += 256) {
        const int g = gbase + i;
        if (g * 4 + 3 < nnz) {
            const float4 v = v4[g];
            const int4   a = a4[g];
            const int4   o = o4[g];
            uint2 e; int p;
            p = atomicAdd(&goff[o.x >> 2], 1);
            e.x = __builtin_bit_cast(unsigned, v.x); e.y = (unsigned)(((o.x & 3) << 12) | a.x);
            bkt[p] = e;
            p = atomicAdd(&goff[o.y >> 2], 1);
            e.x = __builtin_bit_cast(unsigned, v.y); e.y = (unsigned)(((o.y & 3) << 12) | a.y);
            bkt[p] = e;
            p = atomicAdd(&goff[o.z >> 2], 1);
            e.x = __builtin_bit_cast(unsigned, v.z); e.y = (unsigned)(((o.z & 3) << 12) | a.z);
            bkt[p] = e;
            p = atomicAdd(&goff[o.w >> 2], 1);
            e.x = __builtin_bit_cast(unsigned, v.w); e.y = (unsigned)(((o.w & 3) << 12) | a.w);
            bkt[p] = e;
        } else {
            const int ke = (nnz < g * 4 + 4) ? nnz : g * 4 + 4;
            for (int k = g * 4; k < ke; ++k) {
                const int o = iout[k];
                const int p = atomicAdd(&goff[o >> 2], 1);
                uint2 e;
                e.x = __builtin_bit_cast(unsigned, vals[k]);
                e.y = (unsigned)(((o & 3) << 12) | iin[k]);
                bkt[p] = e;
            }
        }
    }
}

// ---- K4: per-cell accumulate (coalesced segment, LDS fp32) -> bf16 W (+x cvt)
__global__ __launch_bounds__(512) void accum_kernel(const uint2* __restrict__ bkt,
                                                    const int* __restrict__ cellbase,
                                                    __bf16* __restrict__ W,
                                                    const f32x4* __restrict__ xin,
                                                    bf16x8* __restrict__ xout) {
    __shared__ float acc[4 * 4096];     // 64 KB
    const int cell = blockIdx.x, tid = threadIdx.x;
    for (int t = tid; t < 4 * 4096; t += 512) acc[t] = 0.f;
    const int s0 = cellbase[cell];
    const int s1 = cellbase[cell + 1];
    __syncthreads();

    for (int s = s0 + tid; s < s1; s += 512) {
        const uint2 e = bkt[s];
        atomicAdd(&acc[((e.y >> 12) & 3u) * 4096 + (e.y & 0xFFFu)],
                  __builtin_bit_cast(float, e.x));
    }
    __syncthreads();

    bf16x8* out = (bf16x8*)(W + (size_t)cell * 4 * 4096);
    for (int t = tid; t < 2048; t += 512) {
        bf16x8 o;
#pragma unroll
        for (int j = 0; j < 8; ++j) o[j] = (__bf16)acc[t * 8 + j];
        out[t] = o;
    }

    // fused x -> bf16 (2048 vec8 per block; 1024 blocks cover 16.7M elems)
    const int xbase = blockIdx.x * 2048;
    for (int t = tid; t < 2048; t += 512) {
        const int idx = xbase + t;
        const f32x4 a = xin[2 * idx];
        const f32x4 bq = xin[2 * idx + 1];
        bf16x8 o;
        o[0] = (__bf16)a[0];  o[1] = (__bf16)a[1];  o[2] = (__bf16)a[2];  o[3] = (__bf16)a[3];
        o[4] = (__bf16)bq[0]; o[5] = (__bf16)bq[1]; o[6] = (__bf16)bq[2]; o[7] = (__bf16)bq[3];
        xout[idx] = o;
    }
}

// ----------------------------------------------------------------- GEMM
// C[M][N] = A[M][K] * B[N][K]^T, all 4096, A/B bf16 row-major, C fp32.
// 256x256 tile, BK=32, 8 waves (2M x 4N), 8x4 16x16x32-bf16 frags/wave.
// 4-deep LDS pipeline (4 x 32 KB = 128 KB), counted vmcnt(8) per K-tile,
// raw s_barrier, setprio(1) around MFMA, bijective XCD blockIdx swizzle.
// [verified rounds 2-3: 126 us, MfmaUtil 47%, bank conflicts 0 — unchanged]
#define GNT 128   // 4096 / BK(=32)

#define STAGE_A(T)                                                            \
  do {                                                                        \
    const __bf16* s_ = gA0 + (size_t)(T) * 32;                                \
    __bf16* d_ = &smem[((T) & 3) * 16384 + tid * 8];                          \
    __builtin_amdgcn_global_load_lds(                                         \
        (const __attribute__((address_space(1))) void*)s_,                    \
        (__attribute__((address_space(3))) void*)d_, 16, 0, 0);               \
    __builtin_amdgcn_global_load_lds(                                         \
        (const __attribute__((address_space(1))) void*)(s_ + (size_t)524288), \
        (__attribute__((address_space(3))) void*)(d_ + 4096), 16, 0, 0);      \
  } while (0)

#define STAGE_B(T)                                                            \
  do {                                                                        \
    const __bf16* s_ = gB0 + (size_t)(T) * 32;                                \
    __bf16* d_ = &smem[((T) & 3) * 16384 + 8192 + tid * 8];                   \
    __builtin_amdgcn_global_load_lds(                                         \
        (const __attribute__((address_space(1))) void*)s_,                    \
        (__attribute__((address_space(3))) void*)d_, 16, 0, 0);               \
    __builtin_amdgcn_global_load_lds(                                         \
        (const __attribute__((address_space(1))) void*)(s_ + (size_t)524288), \
        (__attribute__((address_space(3))) void*)(d_ + 4096), 16, 0, 0);      \
  } while (0)

#define VMW8 asm volatile("s_waitcnt vmcnt(8)" ::: "memory")
#define VMW4 asm volatile("s_waitcnt vmcnt(4)" ::: "memory")
#define VMW0 asm volatile("s_waitcnt vmcnt(0)" ::: "memory")
#define VMWN ((void)0)

#define GTILE(T, DOSTAGE, VMWAIT, ENDBAR)                                     \
  do {                                                                        \
    const __bf16* bp_ = &smem[((T) & 3) * 16384];                             \
    bf16x8 bfr_[4], af_[4];                                                   \
    _Pragma("unroll") for (int j_ = 0; j_ < 4; ++j_)                          \
        bfr_[j_] = *(const bf16x8*)(bp_ + offB[j_]);                          \
    _Pragma("unroll") for (int i_ = 0; i_ < 4; ++i_)                          \
        af_[i_] = *(const bf16x8*)(bp_ + offA[i_]);                           \
    if (DOSTAGE) STAGE_A((T) + 3);                                            \
    __builtin_amdgcn_s_barrier();                                             \
    __builtin_amdgcn_s_setprio(1);                                            \
    _Pragma("unroll") for (int i_ = 0; i_ < 4; ++i_)                          \
        _Pragma("unroll") for (int j_ = 0; j_ < 4; ++j_)                      \
            acc[i_][j_] = __builtin_amdgcn_mfma_f32_16x16x32_bf16(            \
                af_[i_], bfr_[j_], acc[i_][j_], 0, 0, 0);                     \
    __builtin_amdgcn_s_setprio(0);                                            \
    __builtin_amdgcn_s_barrier();                                             \
    _Pragma("unroll") for (int i_ = 0; i_ < 4; ++i_)                          \
        af_[i_] = *(const bf16x8*)(bp_ + offA[4 + i_]);                       \
    if (DOSTAGE) STAGE_B((T) + 3);                                            \
    __builtin_amdgcn_s_barrier();                                             \
    __builtin_amdgcn_s_setprio(1);                                            \
    _Pragma("unroll") for (int i_ = 0; i_ < 4; ++i_)                          \
        _Pragma("unroll") for (int j_ = 0; j_ < 4; ++j_)                      \
            acc[4 + i_][j_] = __builtin_amdgcn_mfma_f32_16x16x32_bf16(        \
                af_[i_], bfr_[j_], acc[4 + i_][j_], 0, 0, 0);                 \
    __builtin_amdgcn_s_setprio(0);                                            \
    asm volatile("s_waitcnt lgkmcnt(0)" ::: "memory");                        \
    VMWAIT;                                                                   \
    if (ENDBAR) __builtin_amdgcn_s_barrier();                                 \
  } while (0)

__global__ __launch_bounds__(512, 2) void gemm_bt_kernel(
    const __bf16* __restrict__ A,
    const __bf16* __restrict__ B,
    float* __restrict__ C) {
    __shared__ __bf16 smem[4 * 16384];   // 128 KB: 4 bufs x (A 8192 | B 8192)

    const int tid   = threadIdx.x;
    const int lane  = tid & 63;
    const int wv    = tid >> 6;
    const int wm    = wv >> 2;
    const int wn    = wv & 3;
    const int row16 = lane & 15;
    const int quad  = lane >> 4;

    const int swz = (blockIdx.x & 7) * 32 + (blockIdx.x >> 3);
    const int bm  = (swz >> 4) * 256;
    const int bn  = (swz & 15) * 256;

    const int sr = tid >> 2;
    const int sq = (tid & 3) ^ ((sr >> 1) & 3);
    const __bf16* gA0 = A + (size_t)(bm + sr) * 4096 + sq * 8;
    const __bf16* gB0 = B + (size_t)(bn + sr) * 4096 + sq * 8;

    int offA[8], offB[4];
#pragma unroll
    for (int i = 0; i < 8; ++i) {
        const int ra = wm * 128 + i * 16 + row16;
        offA[i] = ra * 32 + ((quad ^ ((ra >> 1) & 3)) * 8);
    }
#pragma unroll
    for (int j = 0; j < 4; ++j) {
        const int rb = wn * 64 + j * 16 + row16;
        offB[j] = 8192 + rb * 32 + ((quad ^ ((rb >> 1) & 3)) * 8);
    }

    f32x4 acc[8][4] = {};

    STAGE_A(0); STAGE_B(0);
    STAGE_A(1); STAGE_B(1);
    STAGE_A(2); STAGE_B(2);
    VMW8;
    __builtin_amdgcn_s_barrier();

    int t = 0;
    for (; t < GNT - 3; ++t) GTILE(t, true, VMW8, true);
    GTILE(t, false, VMW4, true); ++t;
    GTILE(t, false, VMW0, true); ++t;
    GTILE(t, false, VMWN, false);

#pragma unroll
    for (int i = 0; i < 8; ++i) {
        const int rbase = bm + wm * 128 + i * 16 + quad * 4;
#pragma unroll
        for (int j = 0; j < 4; ++j) {
            const int col = bn + wn * 64 + j * 16 + row16;
#pragma unroll
            for (int r = 0; r < 4; ++r)
                C[(size_t)(rbase + r) * 4096 + col] = acc[i][j][r];
        }
    }
}

extern "C" void kernel_launch(void* const* d_in, const int* in_sizes, int n_in,
                              void* d_out, int out_size, void* d_ws, size_t ws_size,
                              hipStream_t stream) {
    const float* x    = (const float*)d_in[0];
    const float* vals = (const float*)d_in[1];
    const int*   iin  = (const int*)d_in[2];
    const int*   iout = (const int*)d_in[3];
    float*       C    = (float*)d_out;
    const int    nnz  = in_sizes[1];

    // workspace: Wb 32MB | Xb 32MB | bkt 32MB | cnt 2MB | celltot 4KB | cellbase
    char*   ws       = (char*)d_ws;
    __bf16* Wb       = (__bf16*)ws;
    __bf16* Xb       = (__bf16*)(ws + ((size_t)32 << 20));
    uint2*  bkt      = (uint2*)(ws + ((size_t)64 << 20));
    int*    cnt      = (int*)(ws + ((size_t)96 << 20));
    int*    celltot  = (int*)(ws + ((size_t)96 << 20) + ((size_t)2 << 20));
    int*    cellbase = (int*)(ws + ((size_t)96 << 20) + ((size_t)2 << 20) + 8192);

    hist_kernel<<<NBLK, 256, 0, stream>>>(iout, cnt, nnz);
    scanb_kernel<<<NCELL, 256, 0, stream>>>(cnt, celltot);
    scanc_kernel<<<1, 256, 0, stream>>>(celltot, cellbase);
    scatter_kernel<<<NBLK, 256, 0, stream>>>(vals, iin, iout, cnt, cellbase, bkt, nnz);
    accum_kernel<<<NCELL, 512, 0, stream>>>(bkt, cellbase, Wb, (const f32x4*)x, (bf16x8*)Xb);
    gemm_bt_kernel<<<256, 512, 0, stream>>>(Xb, Wb, C);
}

// Round 5
// 344.234 us; speedup vs baseline: 1.4108x; 1.0998x over previous
//
#include <hip/hip_runtime.h>
#include <hip/hip_bf16.h>

#define IN_SIZE 4096
#define OUT_SIZE 4096
#define BATCH 4096

// 512 source blocks x 8192 entries; 1024 cells of 4 W-rows.
// One-pass reservation scatter: per-cell capacity segments (8192 entries/cell)
// living in d_out (C is dead until the GEMM epilogue rewrites all of it).
#define NBLK 512
#define CHUNK 8192
#define NCELL 1024
#define CELLCAP 8192

typedef __bf16 bf16x8 __attribute__((ext_vector_type(8)));
typedef float f32x4 __attribute__((ext_vector_type(4)));

// ------------------------------------------------------- K0: zero cellcnt
__global__ __launch_bounds__(256) void zero_kernel(int* __restrict__ cellcnt) {
    cellcnt[blockIdx.x * 256 + threadIdx.x & 1023] = 0;   // 4 blocks x 256
}

// ---------------- K1: stage iout in LDS, hist, reserve global ranges, scatter
__global__ __launch_bounds__(512) void scatres_kernel(const float* __restrict__ vals,
                                                      const int* __restrict__ iin,
                                                      const int* __restrict__ iout,
                                                      int* __restrict__ cellcnt,
                                                      uint2* __restrict__ bkt, int nnz) {
    __shared__ int sout[CHUNK];      // 32 KB staged iout
    __shared__ int hist[NCELL];      // 4 KB (then used as countdown)
    __shared__ int gbase[NCELL];     // 4 KB
    const int b = blockIdx.x, tid = threadIdx.x;
    const int base = b * CHUNK;

    for (int c = tid; c < NCELL; c += 512) hist[c] = 0;
    __syncthreads();

    const int4* io4 = (const int4*)(iout + base);
    for (int i = tid; i < CHUNK / 4; i += 512) {
        if (base + i * 4 + 3 < nnz) {
            const int4 o = io4[i];
            ((int4*)sout)[i] = o;
            atomicAdd(&hist[o.x >> 2], 1);
            atomicAdd(&hist[o.y >> 2], 1);
            atomicAdd(&hist[o.z >> 2], 1);
            atomicAdd(&hist[o.w >> 2], 1);
        } else {
            for (int j = 0; j < 4; ++j) {
                const int k = base + i * 4 + j;
                if (k < nnz) {
                    const int o = iout[k];
                    sout[i * 4 + j] = o;
                    atomicAdd(&hist[o >> 2], 1);
                }
            }
        }
    }
    __syncthreads();

    // reserve one contiguous run per non-empty cell
    for (int c = tid; c < NCELL; c += 512)
        gbase[c] = hist[c] ? atomicAdd(&cellcnt[c], hist[c]) : 0;
    __syncthreads();

    // scatter: entry slot = cell*CELLCAP + gbase[cell] + (countdown-1)
    const float4* v4 = (const float4*)(vals + base);
    const int4*   a4 = (const int4*)(iin + base);
    for (int i = tid; i < CHUNK / 4; i += 512) {
        if (base + i * 4 + 3 < nnz) {
            const float4 v = v4[i];
            const int4   a = a4[i];
            const int4   o = ((const int4*)sout)[i];
            int c, l; uint2 e;
            c = o.x >> 2; l = atomicSub(&hist[c], 1) - 1;
            e.x = __builtin_bit_cast(unsigned, v.x); e.y = (unsigned)(((o.x & 3) << 12) | a.x);
            bkt[(size_t)c * CELLCAP + gbase[c] + l] = e;
            c = o.y >> 2; l = atomicSub(&hist[c], 1) - 1;
            e.x = __builtin_bit_cast(unsigned, v.y); e.y = (unsigned)(((o.y & 3) << 12) | a.y);
            bkt[(size_t)c * CELLCAP + gbase[c] + l] = e;
            c = o.z >> 2; l = atomicSub(&hist[c], 1) - 1;
            e.x = __builtin_bit_cast(unsigned, v.z); e.y = (unsigned)(((o.z & 3) << 12) | a.z);
            bkt[(size_t)c * CELLCAP + gbase[c] + l] = e;
            c = o.w >> 2; l = atomicSub(&hist[c], 1) - 1;
            e.x = __builtin_bit_cast(unsigned, v.w); e.y = (unsigned)(((o.w & 3) << 12) | a.w);
            bkt[(size_t)c * CELLCAP + gbase[c] + l] = e;
        } else {
            for (int j = 0; j < 4; ++j) {
                const int k = base + i * 4 + j;
                if (k < nnz) {
                    const int o = sout[i * 4 + j];
                    const int c = o >> 2;
                    const int l = atomicSub(&hist[c], 1) - 1;
                    uint2 e;
                    e.x = __builtin_bit_cast(unsigned, vals[k]);
                    e.y = (unsigned)(((o & 3) << 12) | iin[k]);
                    bkt[(size_t)c * CELLCAP + gbase[c] + l] = e;
                }
            }
        }
    }
}

// ---- K2: per-cell accumulate (packed prefix, LDS fp32) -> bf16 W (+x cvt)
__global__ __launch_bounds__(512) void accum_kernel(const uint2* __restrict__ bkt,
                                                    const int* __restrict__ cellcnt,
                                                    __bf16* __restrict__ W,
                                                    const f32x4* __restrict__ xin,
                                                    bf16x8* __restrict__ xout) {
    __shared__ float acc[4 * 4096];     // 64 KB
    const int cell = blockIdx.x, tid = threadIdx.x;
    for (int t = tid; t < 4 * 4096; t += 512) acc[t] = 0.f;
    int n = cellcnt[cell];
    if (n > CELLCAP) n = CELLCAP;
    __syncthreads();

    const uint2* seg = bkt + (size_t)cell * CELLCAP;
    for (int s = tid; s < n; s += 512) {
        const uint2 e = seg[s];
        atomicAdd(&acc[((e.y >> 12) & 3u) * 4096 + (e.y & 0xFFFu)],
                  __builtin_bit_cast(float, e.x));
    }
    __syncthreads();

    bf16x8* out = (bf16x8*)(W + (size_t)cell * 4 * 4096);
    for (int t = tid; t < 2048; t += 512) {
        bf16x8 o;
#pragma unroll
        for (int j = 0; j < 8; ++j) o[j] = (__bf16)acc[t * 8 + j];
        out[t] = o;
    }

    // fused x -> bf16 (2048 vec8 per block; 1024 blocks cover 16.7M elems)
    const int xbase = blockIdx.x * 2048;
    for (int t = tid; t < 2048; t += 512) {
        const int idx = xbase + t;
        const f32x4 a = xin[2 * idx];
        const f32x4 bq = xin[2 * idx + 1];
        bf16x8 o;
        o[0] = (__bf16)a[0];  o[1] = (__bf16)a[1];  o[2] = (__bf16)a[2];  o[3] = (__bf16)a[3];
        o[4] = (__bf16)bq[0]; o[5] = (__bf16)bq[1]; o[6] = (__bf16)bq[2]; o[7] = (__bf16)bq[3];
        xout[idx] = o;
    }
}

// ----------------------------------------------------------------- GEMM
// C[M][N] = A[M][K] * B[N][K]^T, all 4096, A/B bf16 row-major, C fp32.
// 256x256 tile, BK=32, 8 waves (2M x 4N), 8x4 16x16x32-bf16 frags/wave.
// 4-deep LDS pipeline (4 x 32 KB = 128 KB), counted vmcnt(8) per K-tile,
// raw s_barrier, setprio(1) around MFMA, bijective XCD blockIdx swizzle.
// [verified rounds 2-4: 125 us, MfmaUtil 47%, bank conflicts 0 — unchanged]
#define GNT 128   // 4096 / BK(=32)

#define STAGE_A(T)                                                            \
  do {                                                                        \
    const __bf16* s_ = gA0 + (size_t)(T) * 32;                                \
    __bf16* d_ = &smem[((T) & 3) * 16384 + tid * 8];                          \
    __builtin_amdgcn_global_load_lds(                                         \
        (const __attribute__((address_space(1))) void*)s_,                    \
        (__attribute__((address_space(3))) void*)d_, 16, 0, 0);               \
    __builtin_amdgcn_global_load_lds(                                         \
        (const __attribute__((address_space(1))) void*)(s_ + (size_t)524288), \
        (__attribute__((address_space(3))) void*)(d_ + 4096), 16, 0, 0);      \
  } while (0)

#define STAGE_B(T)                                                            \
  do {                                                                        \
    const __bf16* s_ = gB0 + (size_t)(T) * 32;                                \
    __bf16* d_ = &smem[((T) & 3) * 16384 + 8192 + tid * 8];                   \
    __builtin_amdgcn_global_load_lds(                                         \
        (const __attribute__((address_space(1))) void*)s_,                    \
        (__attribute__((address_space(3))) void*)d_, 16, 0, 0);               \
    __builtin_amdgcn_global_load_lds(                                         \
        (const __attribute__((address_space(1))) void*)(s_ + (size_t)524288), \
        (__attribute__((address_space(3))) void*)(d_ + 4096), 16, 0, 0);      \
  } while (0)

#define VMW8 asm volatile("s_waitcnt vmcnt(8)" ::: "memory")
#define VMW4 asm volatile("s_waitcnt vmcnt(4)" ::: "memory")
#define VMW0 asm volatile("s_waitcnt vmcnt(0)" ::: "memory")
#define VMWN ((void)0)

#define GTILE(T, DOSTAGE, VMWAIT, ENDBAR)                                     \
  do {                                                                        \
    const __bf16* bp_ = &smem[((T) & 3) * 16384];                             \
    bf16x8 bfr_[4], af_[4];                                                   \
    _Pragma("unroll") for (int j_ = 0; j_ < 4; ++j_)                          \
        bfr_[j_] = *(const bf16x8*)(bp_ + offB[j_]);                          \
    _Pragma("unroll") for (int i_ = 0; i_ < 4; ++i_)                          \
        af_[i_] = *(const bf16x8*)(bp_ + offA[i_]);                           \
    if (DOSTAGE) STAGE_A((T) + 3);                                            \
    __builtin_amdgcn_s_barrier();                                             \
    __builtin_amdgcn_s_setprio(1);                                            \
    _Pragma("unroll") for (int i_ = 0; i_ < 4; ++i_)                          \
        _Pragma("unroll") for (int j_ = 0; j_ < 4; ++j_)                      \
            acc[i_][j_] = __builtin_amdgcn_mfma_f32_16x16x32_bf16(            \
                af_[i_], bfr_[j_], acc[i_][j_], 0, 0, 0);                     \
    __builtin_amdgcn_s_setprio(0);                                            \
    __builtin_amdgcn_s_barrier();                                             \
    _Pragma("unroll") for (int i_ = 0; i_ < 4; ++i_)                          \
        af_[i_] = *(const bf16x8*)(bp_ + offA[4 + i_]);                       \
    if (DOSTAGE) STAGE_B((T) + 3);                                            \
    __builtin_amdgcn_s_barrier();                                             \
    __builtin_amdgcn_s_setprio(1);                                            \
    _Pragma("unroll") for (int i_ = 0; i_ < 4; ++i_)                          \
        _Pragma("unroll") for (int j_ = 0; j_ < 4; ++j_)                      \
            acc[4 + i_][j_] = __builtin_amdgcn_mfma_f32_16x16x32_bf16(        \
                af_[i_], bfr_[j_], acc[4 + i_][j_], 0, 0, 0);                 \
    __builtin_amdgcn_s_setprio(0);                                            \
    asm volatile("s_waitcnt lgkmcnt(0)" ::: "memory");                        \
    VMWAIT;                                                                   \
    if (ENDBAR) __builtin_amdgcn_s_barrier();                                 \
  } while (0)

__global__ __launch_bounds__(512, 2) void gemm_bt_kernel(
    const __bf16* __restrict__ A,
    const __bf16* __restrict__ B,
    float* __restrict__ C) {
    __shared__ __bf16 smem[4 * 16384];   // 128 KB: 4 bufs x (A 8192 | B 8192)

    const int tid   = threadIdx.x;
    const int lane  = tid & 63;
    const int wv    = tid >> 6;
    const int wm    = wv >> 2;
    const int wn    = wv & 3;
    const int row16 = lane & 15;
    const int quad  = lane >> 4;

    const int swz = (blockIdx.x & 7) * 32 + (blockIdx.x >> 3);
    const int bm  = (swz >> 4) * 256;
    const int bn  = (swz & 15) * 256;

    const int sr = tid >> 2;
    const int sq = (tid & 3) ^ ((sr >> 1) & 3);
    const __bf16* gA0 = A + (size_t)(bm + sr) * 4096 + sq * 8;
    const __bf16* gB0 = B + (size_t)(bn + sr) * 4096 + sq * 8;

    int offA[8], offB[4];
#pragma unroll
    for (int i = 0; i < 8; ++i) {
        const int ra = wm * 128 + i * 16 + row16;
        offA[i] = ra * 32 + ((quad ^ ((ra >> 1) & 3)) * 8);
    }
#pragma unroll
    for (int j = 0; j < 4; ++j) {
        const int rb = wn * 64 + j * 16 + row16;
        offB[j] = 8192 + rb * 32 + ((quad ^ ((rb >> 1) & 3)) * 8);
    }

    f32x4 acc[8][4] = {};

    STAGE_A(0); STAGE_B(0);
    STAGE_A(1); STAGE_B(1);
    STAGE_A(2); STAGE_B(2);
    VMW8;
    __builtin_amdgcn_s_barrier();

    int t = 0;
    for (; t < GNT - 3; ++t) GTILE(t, true, VMW8, true);
    GTILE(t, false, VMW4, true); ++t;
    GTILE(t, false, VMW0, true); ++t;
    GTILE(t, false, VMWN, false);

#pragma unroll
    for (int i = 0; i < 8; ++i) {
        const int rbase = bm + wm * 128 + i * 16 + quad * 4;
#pragma unroll
        for (int j = 0; j < 4; ++j) {
            const int col = bn + wn * 64 + j * 16 + row16;
#pragma unroll
            for (int r = 0; r < 4; ++r)
                C[(size_t)(rbase + r) * 4096 + col] = acc[i][j][r];
        }
    }
}

extern "C" void kernel_launch(void* const* d_in, const int* in_sizes, int n_in,
                              void* d_out, int out_size, void* d_ws, size_t ws_size,
                              hipStream_t stream) {
    const float* x    = (const float*)d_in[0];
    const float* vals = (const float*)d_in[1];
    const int*   iin  = (const int*)d_in[2];
    const int*   iout = (const int*)d_in[3];
    float*       C    = (float*)d_out;
    const int    nnz  = in_sizes[1];

    // workspace: Wb 32MB | Xb 32MB | cellcnt 4KB  = 64 MB; bkt lives in d_out
    char*   ws      = (char*)d_ws;
    __bf16* Wb      = (__bf16*)ws;
    __bf16* Xb      = (__bf16*)(ws + ((size_t)32 << 20));
    int*    cellcnt = (int*)(ws + ((size_t)64 << 20));
    uint2*  bkt     = (uint2*)d_out;   // 1024 cells x 8192 cap x 8 B = 64 MB

    zero_kernel<<<4, 256, 0, stream>>>(cellcnt);
    scatres_kernel<<<NBLK, 512, 0, stream>>>(vals, iin, iout, cellcnt, bkt, nnz);
    accum_kernel<<<NCELL, 512, 0, stream>>>(bkt, cellcnt, Wb, (const f32x4*)x, (bf16x8*)Xb);
    gemm_bt_kernel<<<256, 512, 0, stream>>>(Xb, Wb, C);
}